// Round 9
// baseline (550.816 us; speedup 1.0000x reference)
//
#include <hip/hip_runtime.h>
#include <hip/hip_bf16.h>

constexpr int MTOK = 1024;   // B*S
constexpr int HDIM = 2048;
constexpr int IDIM = 2048;
constexpr int NEXP = 16;
constexpr int TOPK = 4;
constexpr int NA   = MTOK * TOPK;   // 4096 assignments

#define ALPHA_C 1.702f
#define LIMIT_C 7.0f
#define RMS_EPS 1e-5f

using short8 = __attribute__((ext_vector_type(8))) short;
using f32x4  = __attribute__((ext_vector_type(4))) float;

__device__ __forceinline__ unsigned short f2bf(float f) {
    unsigned u = __builtin_bit_cast(unsigned, f);
    u += 0x7fffu + ((u >> 16) & 1u);     // round-to-nearest-even
    return (unsigned short)(u >> 16);
}

__device__ __forceinline__ unsigned pack2bf(float lo, float hi) {
    return (unsigned)f2bf(lo) | ((unsigned)f2bf(hi) << 16);
}

__device__ __forceinline__ short8 cvt8(const float4 a, const float4 b) {
    union { short8 s; unsigned u[4]; } r;
    r.u[0] = pack2bf(a.x, a.y);
    r.u[1] = pack2bf(a.z, a.w);
    r.u[2] = pack2bf(b.x, b.y);
    r.u[3] = pack2bf(b.z, b.w);
    return r.s;
}

// ---------------- RMSNorm + router + top-k ----------------
__global__ __launch_bounds__(256) void k_router(
    const float* __restrict__ x, const float* __restrict__ norm_w,
    const float* __restrict__ gate_w, const float* __restrict__ gate_b,
    unsigned short* __restrict__ t_bf,
    int* __restrict__ counts, int* __restrict__ idx_of,
    int* __restrict__ slot_of, float* __restrict__ gate_mk)
{
    __shared__ float t_lds[HDIM];
    __shared__ float red[4];
    __shared__ float logits[NEXP];

    const int m   = blockIdx.x;
    const int tid = threadIdx.x;
    const float* xr = x + (size_t)m * HDIM;

    float4 v0 = ((const float4*)xr)[tid * 2];
    float4 v1 = ((const float4*)xr)[tid * 2 + 1];
    float ss = v0.x*v0.x + v0.y*v0.y + v0.z*v0.z + v0.w*v0.w
             + v1.x*v1.x + v1.y*v1.y + v1.z*v1.z + v1.w*v1.w;
    #pragma unroll
    for (int off = 32; off > 0; off >>= 1) ss += __shfl_down(ss, off);
    if ((tid & 63) == 0) red[tid >> 6] = ss;
    __syncthreads();
    float tot = red[0] + red[1] + red[2] + red[3];
    float scale = rsqrtf(tot / (float)HDIM + RMS_EPS);

    float4 n0 = ((const float4*)norm_w)[tid * 2];
    float4 n1 = ((const float4*)norm_w)[tid * 2 + 1];
    float t[8];
    t[0]=v0.x*scale*n0.x; t[1]=v0.y*scale*n0.y; t[2]=v0.z*scale*n0.z; t[3]=v0.w*scale*n0.w;
    t[4]=v1.x*scale*n1.x; t[5]=v1.y*scale*n1.y; t[6]=v1.z*scale*n1.z; t[7]=v1.w*scale*n1.w;
    short8 pk;
    #pragma unroll
    for (int j = 0; j < 8; ++j) {
        t_lds[tid * 8 + j] = t[j];
        pk[j] = (short)f2bf(t[j]);
    }
    *(short8*)(t_bf + (size_t)m * HDIM + tid * 8) = pk;
    __syncthreads();

    const int e = tid >> 4, j = tid & 15;
    const float4* gw4 = (const float4*)(gate_w + (size_t)e * HDIM);
    const float4* tl4 = (const float4*)t_lds;
    float part = 0.f;
    for (int h4 = j; h4 < HDIM / 4; h4 += 16) {
        float4 g = gw4[h4], tv = tl4[h4];
        part += g.x*tv.x + g.y*tv.y + g.z*tv.z + g.w*tv.w;
    }
    #pragma unroll
    for (int off = 8; off > 0; off >>= 1) part += __shfl_xor(part, off);
    if (j == 0) logits[e] = part + gate_b[e];
    __syncthreads();

    if (tid == 0) {
        float lv[NEXP];
        #pragma unroll
        for (int q = 0; q < NEXP; ++q) lv[q] = logits[q];
        int   sel[TOPK];
        float sv[TOPK];
        #pragma unroll
        for (int k = 0; k < TOPK; ++k) {
            float best = -1e30f; int bi = 0;
            for (int q = 0; q < NEXP; ++q)
                if (lv[q] > best) { best = lv[q]; bi = q; }
            sel[k] = bi; sv[k] = best; lv[bi] = -1e30f;
        }
        float mx = sv[0], s = 0.f, g[TOPK];
        #pragma unroll
        for (int k = 0; k < TOPK; ++k) { g[k] = __expf(sv[k] - mx); s += g[k]; }
        float inv = 1.f / s;
        #pragma unroll
        for (int k = 0; k < TOPK; ++k) {
            int a = m * TOPK + k;
            int slot = atomicAdd(&counts[sel[k]], 1);
            idx_of[a]  = sel[k];
            slot_of[a] = slot;
            gate_mk[a] = g[k] * inv;
        }
    }
}

// ---------------- scatter tokens into compact per-expert rows ----------------
__global__ void k_remap(const int* __restrict__ idx_of, const int* __restrict__ slot_of,
                        const int* __restrict__ counts,
                        int* __restrict__ token_of, int* __restrict__ rowidx)
{
    int a = blockIdx.x * blockDim.x + threadIdx.x;
    if (a >= NA) return;
    int e = idx_of[a];
    int off = 0;
    for (int q = 0; q < NEXP; ++q) off += (q < e) ? counts[q] : 0;
    int r = off + slot_of[a];
    token_of[r] = a >> 2;
    rowidx[a]   = r;
}

// ---------------- GEMM1 + bias + clamped SwiGLU -> act (bf16) ----------------
// BM=320 x 32 B-cols (=16 i-pairs), BK=64, 32 steps. 4 waves; wave wv owns
// rows [wv*80,+80). Low-VGPR (~145): acc[5][2], B = 4 named sets x 2 float4
// (issue t+3 at t, publish at t+2), A = 2 sets reloaded post-use.
// __launch_bounds__(256,3) -> 3 blocks/CU x 4 waves. lgkmcnt-only barriers.
__global__ __launch_bounds__(256, 3) void k_gemm1(
    const unsigned short* __restrict__ t_bf,
    const float* __restrict__ w1, const float* __restrict__ b1,
    const int* __restrict__ counts, const int* __restrict__ token_of,
    unsigned short* __restrict__ act)
{
    __shared__ unsigned char lB[2][2][2560];   // [buf][kk][32 cols x 80B]

    const int e = blockIdx.z;
    int ne = 0, roff = 0;
    #pragma unroll
    for (int q = 0; q < NEXP; ++q) {
        int cq = counts[q];
        roff += (q < e) ? cq : 0;
        ne    = (q == e) ? cq : ne;
    }
    const int brow = blockIdx.y * 320;
    if (brow >= ne) return;
    const int i0 = blockIdx.x * 16;          // 16 i-values per block
    const int tid = threadIdx.x;

    const int wv = tid >> 6, ln = tid & 63;
    const int lr = ln & 15, lk = ln >> 4;
    const int bc = tid >> 3, bp = tid & 7;   // B staging: col bc, 8-float chunk bp

    const unsigned short* aptr[5];
    #pragma unroll
    for (int mf = 0; mf < 5; ++mf) {
        int rg = brow + wv * 80 + mf * 16 + lr;
        int tok = token_of[roff + (rg < ne ? rg : 0)];
        aptr[mf] = t_bf + (size_t)tok * HDIM + lk * 8;
    }
    // col bc<16 -> o=2(i0+bc) (a); bc>=16 -> o=2(i0+bc-16)+1 (b)
    const int o = (bc < 16) ? (2 * (i0 + bc)) : (2 * (i0 + bc - 16) + 1);
    const float* bsrc = w1 + ((size_t)e * (2 * IDIM) + o) * HDIM + bp * 8;

    float4 bS0[2], bS1[2], bS2[2], bS3[2];
    short8 aA0[5], aA1[5];
    f32x4  acc[5][2] = {};

    constexpr int NT = 32;   // HDIM / 64

    {   // tile 0 direct publish
        float4 p0 = *(const float4*)(bsrc);
        float4 p1 = *(const float4*)(bsrc + 4);
        *(short8*)(&lB[0][bp >> 2][bc * 80 + (bp & 3) * 16]) = cvt8(p0, p1);
    }
    bS1[0] = *(const float4*)(bsrc + 64);   bS1[1] = *(const float4*)(bsrc + 68);
    bS2[0] = *(const float4*)(bsrc + 128);  bS2[1] = *(const float4*)(bsrc + 132);
    bS3[0] = *(const float4*)(bsrc + 192);  bS3[1] = *(const float4*)(bsrc + 196);
    #pragma unroll
    for (int mf = 0; mf < 5; ++mf) {
        aA0[mf] = *(const short8*)(aptr[mf]);
        aA1[mf] = *(const short8*)(aptr[mf] + 32);
    }
    asm volatile("s_waitcnt lgkmcnt(0)" ::: "memory");
    __builtin_amdgcn_s_barrier();

#define GSTEP(T_, SPUB, SISS)                                                            \
    {                                                                                    \
        const int t_ = (T_);                                                             \
        const int c_ = t_ & 1;                                                           \
        if (t_ + 1 < NT)   /* publish tile t+1 */                                        \
            *(short8*)(&lB[c_ ^ 1][bp >> 2][bc * 80 + (bp & 3) * 16]) =                  \
                cvt8(SPUB[0], SPUB[1]);                                                  \
        if (t_ + 3 < NT) { /* issue tile t+3 */                                          \
            SPUB[0] = SPUB[0]; /* keep macro hygiene */                                  \
            SISS[0] = *(const float4*)(bsrc + (t_ + 3) * 64);                            \
            SISS[1] = *(const float4*)(bsrc + (t_ + 3) * 64 + 4);                        \
        }                                                                                \
        short8 bfr[2];                                                                   \
        _Pragma("unroll")                                                                \
        for (int n = 0; n < 2; ++n)                                                      \
            bfr[n] = *(const short8*)(&lB[c_][0][(n * 16 + lr) * 80 + lk * 16]);         \
        _Pragma("unroll")                                                                \
        for (int mf = 0; mf < 5; ++mf)                                                   \
            _Pragma("unroll")                                                            \
            for (int n = 0; n < 2; ++n)                                                  \
                acc[mf][n] = __builtin_amdgcn_mfma_f32_16x16x32_bf16(                    \
                    aA0[mf], bfr[n], acc[mf][n], 0, 0, 0);                               \
        _Pragma("unroll")                                                                \
        for (int n = 0; n < 2; ++n)                                                      \
            bfr[n] = *(const short8*)(&lB[c_][1][(n * 16 + lr) * 80 + lk * 16]);         \
        _Pragma("unroll")                                                                \
        for (int mf = 0; mf < 5; ++mf)                                                   \
            _Pragma("unroll")                                                            \
            for (int n = 0; n < 2; ++n)                                                  \
                acc[mf][n] = __builtin_amdgcn_mfma_f32_16x16x32_bf16(                    \
                    aA1[mf], bfr[n], acc[mf][n], 0, 0, 0);                               \
        if (t_ + 1 < NT) { /* reload A for step t+1 (L2-hot) */                          \
            _Pragma("unroll")                                                            \
            for (int mf = 0; mf < 5; ++mf) {                                             \
                aA0[mf] = *(const short8*)(aptr[mf] + (t_ + 1) * 64);                    \
                aA1[mf] = *(const short8*)(aptr[mf] + (t_ + 1) * 64 + 32);               \
            }                                                                            \
        }                                                                                \
        asm volatile("s_waitcnt lgkmcnt(0)" ::: "memory");                               \
        __builtin_amdgcn_s_barrier();                                                    \
    }

    for (int t8 = 0; t8 < NT / 4; ++t8) {
        const int tb = t8 * 4;
        GSTEP(tb + 0, bS1, bS3)
        GSTEP(tb + 1, bS2, bS0)
        GSTEP(tb + 2, bS3, bS1)
        GSTEP(tb + 3, bS0, bS2)
    }
#undef GSTEP

    {
        const int i = i0 + lr;
        const float ba = b1[(size_t)e * (2 * IDIM) + 2 * i];
        const float bb = b1[(size_t)e * (2 * IDIM) + 2 * i + 1];
        #pragma unroll
        for (int mf = 0; mf < 5; ++mf) {
            #pragma unroll
            for (int r = 0; r < 4; ++r) {
                const int rg = brow + wv * 80 + mf * 16 + lk * 4 + r;
                if (rg < ne) {
                    float ha = acc[mf][0][r] + ba;
                    float hb = acc[mf][1][r] + bb;
                    float a = fminf(ha, LIMIT_C);
                    float b = fminf(fmaxf(hb, -LIMIT_C), LIMIT_C);
                    float s = 1.f / (1.f + __expf(-ALPHA_C * a));
                    act[(size_t)(roff + rg) * IDIM + i] = f2bf(a * s * (b + 1.f));
                }
            }
        }
    }
}

// ---------------- GEMM2 + bias -> ybuf (bf16, un-gated) ----------------
__global__ __launch_bounds__(256, 3) void k_gemm2(
    const unsigned short* __restrict__ act,
    const float* __restrict__ w2, const float* __restrict__ b2,
    const int* __restrict__ counts, const int* __restrict__ token_of,
    unsigned short* __restrict__ ybuf)
{
    __shared__ unsigned char lB[2][2][2560];

    const int e = blockIdx.z;
    int ne = 0, roff = 0;
    #pragma unroll
    for (int q = 0; q < NEXP; ++q) {
        int cq = counts[q];
        roff += (q < e) ? cq : 0;
        ne    = (q == e) ? cq : ne;
    }
    const int brow = blockIdx.y * 320;
    if (brow >= ne) return;
    const int d0 = blockIdx.x * 32;
    const int tid = threadIdx.x;

    const int wv = tid >> 6, ln = tid & 63;
    const int lr = ln & 15, lk = ln >> 4;
    const int bc = tid >> 3, bp = tid & 7;

    const unsigned short* aptr[5];
    #pragma unroll
    for (int mf = 0; mf < 5; ++mf) {
        int rg = brow + wv * 80 + mf * 16 + lr;
        int rc = (rg < ne) ? rg : 0;
        aptr[mf] = act + (size_t)(roff + rc) * IDIM + lk * 8;
    }
    const float* bsrc = w2 + ((size_t)e * HDIM + d0 + bc) * IDIM + bp * 8;

    float4 bS0[2], bS1[2], bS2[2], bS3[2];
    short8 aA0[5], aA1[5];
    f32x4  acc[5][2] = {};

    constexpr int NT = 32;   // IDIM / 64

    {
        float4 p0 = *(const float4*)(bsrc);
        float4 p1 = *(const float4*)(bsrc + 4);
        *(short8*)(&lB[0][bp >> 2][bc * 80 + (bp & 3) * 16]) = cvt8(p0, p1);
    }
    bS1[0] = *(const float4*)(bsrc + 64);   bS1[1] = *(const float4*)(bsrc + 68);
    bS2[0] = *(const float4*)(bsrc + 128);  bS2[1] = *(const float4*)(bsrc + 132);
    bS3[0] = *(const float4*)(bsrc + 192);  bS3[1] = *(const float4*)(bsrc + 196);
    #pragma unroll
    for (int mf = 0; mf < 5; ++mf) {
        aA0[mf] = *(const short8*)(aptr[mf]);
        aA1[mf] = *(const short8*)(aptr[mf] + 32);
    }
    asm volatile("s_waitcnt lgkmcnt(0)" ::: "memory");
    __builtin_amdgcn_s_barrier();

#define GSTEP(T_, SPUB, SISS)                                                            \
    {                                                                                    \
        const int t_ = (T_);                                                             \
        const int c_ = t_ & 1;                                                           \
        if (t_ + 1 < NT)                                                                 \
            *(short8*)(&lB[c_ ^ 1][bp >> 2][bc * 80 + (bp & 3) * 16]) =                  \
                cvt8(SPUB[0], SPUB[1]);                                                  \
        if (t_ + 3 < NT) {                                                               \
            SISS[0] = *(const float4*)(bsrc + (t_ + 3) * 64);                            \
            SISS[1] = *(const float4*)(bsrc + (t_ + 3) * 64 + 4);                        \
        }                                                                                \
        short8 bfr[2];                                                                   \
        _Pragma("unroll")                                                                \
        for (int n = 0; n < 2; ++n)                                                      \
            bfr[n] = *(const short8*)(&lB[c_][0][(n * 16 + lr) * 80 + lk * 16]);         \
        _Pragma("unroll")                                                                \
        for (int mf = 0; mf < 5; ++mf)                                                   \
            _Pragma("unroll")                                                            \
            for (int n = 0; n < 2; ++n)                                                  \
                acc[mf][n] = __builtin_amdgcn_mfma_f32_16x16x32_bf16(                    \
                    aA0[mf], bfr[n], acc[mf][n], 0, 0, 0);                               \
        _Pragma("unroll")                                                                \
        for (int n = 0; n < 2; ++n)                                                      \
            bfr[n] = *(const short8*)(&lB[c_][1][(n * 16 + lr) * 80 + lk * 16]);         \
        _Pragma("unroll")                                                                \
        for (int mf = 0; mf < 5; ++mf)                                                   \
            _Pragma("unroll")                                                            \
            for (int n = 0; n < 2; ++n)                                                  \
                acc[mf][n] = __builtin_amdgcn_mfma_f32_16x16x32_bf16(                    \
                    aA1[mf], bfr[n], acc[mf][n], 0, 0, 0);                               \
        if (t_ + 1 < NT) {                                                               \
            _Pragma("unroll")                                                            \
            for (int mf = 0; mf < 5; ++mf) {                                             \
                aA0[mf] = *(const short8*)(aptr[mf] + (t_ + 1) * 64);                    \
                aA1[mf] = *(const short8*)(aptr[mf] + (t_ + 1) * 64 + 32);               \
            }                                                                            \
        }                                                                                \
        asm volatile("s_waitcnt lgkmcnt(0)" ::: "memory");                               \
        __builtin_amdgcn_s_barrier();                                                    \
    }

    for (int t8 = 0; t8 < NT / 4; ++t8) {
        const int tb = t8 * 4;
        GSTEP(tb + 0, bS1, bS3)
        GSTEP(tb + 1, bS2, bS0)
        GSTEP(tb + 2, bS3, bS1)
        GSTEP(tb + 3, bS0, bS2)
    }
#undef GSTEP

    #pragma unroll
    for (int mf = 0; mf < 5; ++mf) {
        #pragma unroll
        for (int r = 0; r < 4; ++r) {
            const int rg = brow + wv * 80 + mf * 16 + lk * 4 + r;
            if (rg >= ne) continue;
            unsigned short* yrow = ybuf + (size_t)(roff + rg) * HDIM;
            #pragma unroll
            for (int n = 0; n < 2; ++n) {
                const int d = d0 + n * 16 + lr;
                yrow[d] = f2bf(acc[mf][n][r] + b2[(size_t)e * HDIM + d]);
            }
        }
    }
}

// ---------------- combine: out = x + sum_k gate_k * ybuf[row_k] ----------------
__global__ __launch_bounds__(256) void k_comb(
    const float* __restrict__ x, const unsigned short* __restrict__ ybuf,
    const int* __restrict__ rowidx, const float* __restrict__ gate_mk,
    float* __restrict__ out)
{
    __shared__ int   rws[TOPK];
    __shared__ float gws[TOPK];
    const int m = blockIdx.x;
    const int tid = threadIdx.x;
    if (tid < TOPK) {
        rws[tid] = rowidx[m * TOPK + tid];
        gws[tid] = gate_mk[m * TOPK + tid];
    }
    __syncthreads();
    const int d = tid * 8;
    float4 o0 = ((const float4*)(x + (size_t)m * HDIM + d))[0];
    float4 o1 = ((const float4*)(x + (size_t)m * HDIM + d))[1];
    #pragma unroll
    for (int k = 0; k < TOPK; ++k) {
        const float g = gws[k];
        short8 y = *(const short8*)(ybuf + (size_t)rws[k] * HDIM + d);
        float yv[8];
        #pragma unroll
        for (int j = 0; j < 8; ++j) {
            unsigned u = ((unsigned)(unsigned short)y[j]) << 16;
            yv[j] = __builtin_bit_cast(float, u);
        }
        o0.x += g * yv[0]; o0.y += g * yv[1]; o0.z += g * yv[2]; o0.w += g * yv[3];
        o1.x += g * yv[4]; o1.y += g * yv[5]; o1.z += g * yv[6]; o1.w += g * yv[7];
    }
    ((float4*)(out + (size_t)m * HDIM + d))[0] = o0;
    ((float4*)(out + (size_t)m * HDIM + d))[1] = o1;
}

extern "C" void kernel_launch(void* const* d_in, const int* in_sizes, int n_in,
                              void* d_out, int out_size, void* d_ws, size_t ws_size,
                              hipStream_t stream) {
    const float* x      = (const float*)d_in[0];
    const float* norm_w = (const float*)d_in[1];
    const float* gate_w = (const float*)d_in[2];
    const float* gate_b = (const float*)d_in[3];
    const float* w1     = (const float*)d_in[4];
    const float* b1     = (const float*)d_in[5];
    const float* w2     = (const float*)d_in[6];
    const float* b2     = (const float*)d_in[7];
    float* out = (float*)d_out;

    char* ws = (char*)d_ws;
    size_t off = 0;
    unsigned short* t_bf = (unsigned short*)(ws + off); off += (size_t)MTOK * HDIM * 2;  // 4 MB
    unsigned short* actb = (unsigned short*)(ws + off); off += (size_t)NA * IDIM * 2;    // 16.8 MB
    unsigned short* ybuf = (unsigned short*)(ws + off); off += (size_t)NA * HDIM * 2;    // 16.8 MB
    int*   counts   = (int*)(ws + off);   off += 256;
    int*   idx_of   = (int*)(ws + off);   off += (size_t)NA * 4;
    int*   slot_of  = (int*)(ws + off);   off += (size_t)NA * 4;
    float* gate_mk  = (float*)(ws + off); off += (size_t)NA * 4;
    int*   token_of = (int*)(ws + off);   off += (size_t)NA * 4;
    int*   rowidx   = (int*)(ws + off);   off += (size_t)NA * 4;

    (void)hipMemsetAsync(counts, 0, 256, stream);
    k_router<<<MTOK, 256, 0, stream>>>(x, norm_w, gate_w, gate_b, t_bf,
                                       counts, idx_of, slot_of, gate_mk);
    k_remap<<<NA / 256, 256, 0, stream>>>(idx_of, slot_of, counts,
                                          token_of, rowidx);
    k_gemm1<<<dim3(IDIM / 16, (MTOK + 319) / 320, NEXP), 256, 0, stream>>>(
        t_bf, w1, b1, counts, token_of, actb);
    k_gemm2<<<dim3(HDIM / 32, (MTOK + 319) / 320, NEXP), 256, 0, stream>>>(
        actb, w2, b2, counts, token_of, ybuf);
    k_comb<<<MTOK, 256, 0, stream>>>(x, ybuf, rowidx, gate_mk, out);
}

// Round 10
// 410.860 us; speedup vs baseline: 1.3406x; 1.3406x over previous
//
#include <hip/hip_runtime.h>
#include <hip/hip_bf16.h>

constexpr int MTOK = 1024;   // B*S
constexpr int HDIM = 2048;
constexpr int IDIM = 2048;
constexpr int NEXP = 16;
constexpr int TOPK = 4;
constexpr int NA   = MTOK * TOPK;   // 4096 assignments

#define ALPHA_C 1.702f
#define LIMIT_C 7.0f
#define RMS_EPS 1e-5f

using short8 = __attribute__((ext_vector_type(8))) short;
using f32x4  = __attribute__((ext_vector_type(4))) float;

__device__ __forceinline__ unsigned short f2bf(float f) {
    unsigned u = __builtin_bit_cast(unsigned, f);
    u += 0x7fffu + ((u >> 16) & 1u);     // round-to-nearest-even
    return (unsigned short)(u >> 16);
}

__device__ __forceinline__ unsigned pack2bf(float lo, float hi) {
    return (unsigned)f2bf(lo) | ((unsigned)f2bf(hi) << 16);
}

__device__ __forceinline__ short8 cvt8(const float4 a, const float4 b) {
    union { short8 s; unsigned u[4]; } r;
    r.u[0] = pack2bf(a.x, a.y);
    r.u[1] = pack2bf(a.z, a.w);
    r.u[2] = pack2bf(b.x, b.y);
    r.u[3] = pack2bf(b.z, b.w);
    return r.s;
}

// ---------------- RMSNorm + router + top-k ----------------
__global__ __launch_bounds__(256) void k_router(
    const float* __restrict__ x, const float* __restrict__ norm_w,
    const float* __restrict__ gate_w, const float* __restrict__ gate_b,
    unsigned short* __restrict__ t_bf,
    int* __restrict__ counts, int* __restrict__ idx_of,
    int* __restrict__ slot_of, float* __restrict__ gate_mk)
{
    __shared__ float t_lds[HDIM];
    __shared__ float red[4];
    __shared__ float logits[NEXP];

    const int m   = blockIdx.x;
    const int tid = threadIdx.x;
    const float* xr = x + (size_t)m * HDIM;

    float4 v0 = ((const float4*)xr)[tid * 2];
    float4 v1 = ((const float4*)xr)[tid * 2 + 1];
    float ss = v0.x*v0.x + v0.y*v0.y + v0.z*v0.z + v0.w*v0.w
             + v1.x*v1.x + v1.y*v1.y + v1.z*v1.z + v1.w*v1.w;
    #pragma unroll
    for (int off = 32; off > 0; off >>= 1) ss += __shfl_down(ss, off);
    if ((tid & 63) == 0) red[tid >> 6] = ss;
    __syncthreads();
    float tot = red[0] + red[1] + red[2] + red[3];
    float scale = rsqrtf(tot / (float)HDIM + RMS_EPS);

    float4 n0 = ((const float4*)norm_w)[tid * 2];
    float4 n1 = ((const float4*)norm_w)[tid * 2 + 1];
    float t[8];
    t[0]=v0.x*scale*n0.x; t[1]=v0.y*scale*n0.y; t[2]=v0.z*scale*n0.z; t[3]=v0.w*scale*n0.w;
    t[4]=v1.x*scale*n1.x; t[5]=v1.y*scale*n1.y; t[6]=v1.z*scale*n1.z; t[7]=v1.w*scale*n1.w;
    short8 pk;
    #pragma unroll
    for (int j = 0; j < 8; ++j) {
        t_lds[tid * 8 + j] = t[j];
        pk[j] = (short)f2bf(t[j]);
    }
    *(short8*)(t_bf + (size_t)m * HDIM + tid * 8) = pk;
    __syncthreads();

    const int e = tid >> 4, j = tid & 15;
    const float4* gw4 = (const float4*)(gate_w + (size_t)e * HDIM);
    const float4* tl4 = (const float4*)t_lds;
    float part = 0.f;
    for (int h4 = j; h4 < HDIM / 4; h4 += 16) {
        float4 g = gw4[h4], tv = tl4[h4];
        part += g.x*tv.x + g.y*tv.y + g.z*tv.z + g.w*tv.w;
    }
    #pragma unroll
    for (int off = 8; off > 0; off >>= 1) part += __shfl_xor(part, off);
    if (j == 0) logits[e] = part + gate_b[e];
    __syncthreads();

    if (tid == 0) {
        float lv[NEXP];
        #pragma unroll
        for (int q = 0; q < NEXP; ++q) lv[q] = logits[q];
        int   sel[TOPK];
        float sv[TOPK];
        #pragma unroll
        for (int k = 0; k < TOPK; ++k) {
            float best = -1e30f; int bi = 0;
            for (int q = 0; q < NEXP; ++q)
                if (lv[q] > best) { best = lv[q]; bi = q; }
            sel[k] = bi; sv[k] = best; lv[bi] = -1e30f;
        }
        float mx = sv[0], s = 0.f, g[TOPK];
        #pragma unroll
        for (int k = 0; k < TOPK; ++k) { g[k] = __expf(sv[k] - mx); s += g[k]; }
        float inv = 1.f / s;
        #pragma unroll
        for (int k = 0; k < TOPK; ++k) {
            int a = m * TOPK + k;
            int slot = atomicAdd(&counts[sel[k]], 1);
            idx_of[a]  = sel[k];
            slot_of[a] = slot;
            gate_mk[a] = g[k] * inv;
        }
    }
}

// ---------------- scatter tokens into compact per-expert rows ----------------
__global__ void k_remap(const int* __restrict__ idx_of, const int* __restrict__ slot_of,
                        const int* __restrict__ counts,
                        int* __restrict__ token_of, int* __restrict__ rowidx)
{
    int a = blockIdx.x * blockDim.x + threadIdx.x;
    if (a >= NA) return;
    int e = idx_of[a];
    int off = 0;
    for (int q = 0; q < NEXP; ++q) off += (q < e) ? counts[q] : 0;
    int r = off + slot_of[a];
    token_of[r] = a >> 2;
    rowidx[a]   = r;
}

// ---------------- GEMM1 + bias + clamped SwiGLU -> act (bf16) ----------------
// BM=320 x 64 cols, BK=32, NT=64 steps. Per step, ISSUE ORDER IS THE POINT:
//   1. A(t+1) loads (oldest-used-first pipeline, consumed next step)
//   2. B(t+3) loads (consumed via publish 2 steps later)
//   3. sched_barrier(0) pins the load cluster at the top
//   4. publish B(t+1) (cvt waits counted vmcnt, ~14 younger ops in queue)
//   5. ds_read + 20 MFMA (A(t) wait is counted vmcnt(~7), NOT vmcnt(0))
//   6. lgkmcnt(0); s_barrier  -- vmem NEVER drained in-loop
__global__ __launch_bounds__(256, 2) void k_gemm1(
    const unsigned short* __restrict__ t_bf,
    const float* __restrict__ w1, const float* __restrict__ b1,
    const int* __restrict__ counts, const int* __restrict__ token_of,
    unsigned short* __restrict__ act)
{
    __shared__ unsigned char lB[2][5120];   // [buf][64 cols x 80B]

    const int e = blockIdx.z;
    int ne = 0, roff = 0;
    #pragma unroll
    for (int q = 0; q < NEXP; ++q) {
        int cq = counts[q];
        roff += (q < e) ? cq : 0;
        ne    = (q == e) ? cq : ne;
    }
    const int brow = blockIdx.y * 320;
    if (brow >= ne) return;
    const int i0 = blockIdx.x * 32;
    const int tid = threadIdx.x;

    const int wv = tid >> 6, ln = tid & 63;
    const int lr = ln & 15, lk = ln >> 4;
    const int br = tid >> 2, bp = tid & 3;   // B staging: col br, 8-float chunk bp

    const unsigned short* aptr[5];
    #pragma unroll
    for (int mf = 0; mf < 5; ++mf) {
        int rg = brow + wv * 80 + mf * 16 + lr;
        int tok = token_of[roff + (rg < ne ? rg : 0)];
        aptr[mf] = t_bf + (size_t)tok * HDIM + lk * 8;
    }
    const int o = (br < 32) ? (2 * (i0 + br)) : (2 * (i0 + br - 32) + 1);
    const float* bsrc = w1 + ((size_t)e * (2 * IDIM) + o) * HDIM + bp * 8;

    short8 aE[5], aO[5];
    float4 bS0[2], bS1[2], bS2[2], bS3[2];
    f32x4  acc[5][4] = {};

    constexpr int NT = 64;   // HDIM / 32

    // prologue: A(0)->aE; B tile0 sync-publish; preload bS1<-t1, bS2<-t2
    #pragma unroll
    for (int mf = 0; mf < 5; ++mf) aE[mf] = *(const short8*)(aptr[mf]);
    {
        float4 p0 = *(const float4*)(bsrc);
        float4 p1 = *(const float4*)(bsrc + 4);
        *(short8*)(&lB[0][br * 80 + bp * 16]) = cvt8(p0, p1);
    }
    bS1[0] = *(const float4*)(bsrc + 32);  bS1[1] = *(const float4*)(bsrc + 36);
    bS2[0] = *(const float4*)(bsrc + 64);  bS2[1] = *(const float4*)(bsrc + 68);
    asm volatile("s_waitcnt lgkmcnt(0)" ::: "memory");
    __builtin_amdgcn_s_barrier();

#define GSTEP(T_, AU, AP, SPUB, SISS)                                                    \
    {                                                                                    \
        const int t_ = (T_);                                                             \
        if (t_ + 1 < NT) {  /* 1. A(t+1) first */                                        \
            _Pragma("unroll")                                                            \
            for (int mf = 0; mf < 5; ++mf)                                               \
                AP[mf] = *(const short8*)(aptr[mf] + (t_ + 1) * 32);                     \
        }                                                                                \
        if (t_ + 3 < NT) {  /* 2. B(t+3) second */                                       \
            SISS[0] = *(const float4*)(bsrc + (t_ + 3) * 32);                            \
            SISS[1] = *(const float4*)(bsrc + (t_ + 3) * 32 + 4);                        \
        }                                                                                \
        __builtin_amdgcn_sched_barrier(0);  /* 3. pin loads at top */                    \
        if (t_ + 1 < NT)    /* 4. publish B(t+1) */                                      \
            *(short8*)(&lB[(t_ + 1) & 1][br * 80 + bp * 16]) = cvt8(SPUB[0], SPUB[1]);   \
        short8 bfr[4];      /* 5. compute tile t */                                      \
        _Pragma("unroll")                                                                \
        for (int n = 0; n < 4; ++n)                                                      \
            bfr[n] = *(const short8*)(&lB[t_ & 1][(n * 16 + lr) * 80 + lk * 16]);        \
        _Pragma("unroll")                                                                \
        for (int mf = 0; mf < 5; ++mf)                                                   \
            _Pragma("unroll")                                                            \
            for (int n = 0; n < 4; ++n)                                                  \
                acc[mf][n] = __builtin_amdgcn_mfma_f32_16x16x32_bf16(                    \
                    AU[mf], bfr[n], acc[mf][n], 0, 0, 0);                                \
        asm volatile("s_waitcnt lgkmcnt(0)" ::: "memory");                               \
        __builtin_amdgcn_s_barrier();                                                    \
    }

    for (int t4 = 0; t4 < NT / 4; ++t4) {
        const int tb = t4 * 4;
        GSTEP(tb + 0, aE, aO, bS1, bS3)
        GSTEP(tb + 1, aO, aE, bS2, bS0)
        GSTEP(tb + 2, aE, aO, bS3, bS1)
        GSTEP(tb + 3, aO, aE, bS0, bS2)
    }
#undef GSTEP

    #pragma unroll
    for (int n = 0; n < 2; ++n) {
        const int i = i0 + n * 16 + lr;
        const float ba = b1[(size_t)e * (2 * IDIM) + 2 * i];
        const float bb = b1[(size_t)e * (2 * IDIM) + 2 * i + 1];
        #pragma unroll
        for (int mf = 0; mf < 5; ++mf) {
            #pragma unroll
            for (int r = 0; r < 4; ++r) {
                const int rg = brow + wv * 80 + mf * 16 + lk * 4 + r;
                if (rg < ne) {
                    float ha = acc[mf][n][r] + ba;
                    float hb = acc[mf][n + 2][r] + bb;
                    float a = fminf(ha, LIMIT_C);
                    float b = fminf(fmaxf(hb, -LIMIT_C), LIMIT_C);
                    float s = 1.f / (1.f + __expf(-ALPHA_C * a));
                    act[(size_t)(roff + rg) * IDIM + i] = f2bf(a * s * (b + 1.f));
                }
            }
        }
    }
}

// ---------------- GEMM2 + bias -> ybuf (bf16, un-gated) ----------------
__global__ __launch_bounds__(256, 2) void k_gemm2(
    const unsigned short* __restrict__ act,
    const float* __restrict__ w2, const float* __restrict__ b2,
    const int* __restrict__ counts, const int* __restrict__ token_of,
    unsigned short* __restrict__ ybuf)
{
    __shared__ unsigned char lB[2][5120];

    const int e = blockIdx.z;
    int ne = 0, roff = 0;
    #pragma unroll
    for (int q = 0; q < NEXP; ++q) {
        int cq = counts[q];
        roff += (q < e) ? cq : 0;
        ne    = (q == e) ? cq : ne;
    }
    const int brow = blockIdx.y * 320;
    if (brow >= ne) return;
    const int d0 = blockIdx.x * 64;
    const int tid = threadIdx.x;

    const int wv = tid >> 6, ln = tid & 63;
    const int lr = ln & 15, lk = ln >> 4;
    const int br = tid >> 2, bp = tid & 3;

    const unsigned short* aptr[5];
    #pragma unroll
    for (int mf = 0; mf < 5; ++mf) {
        int rg = brow + wv * 80 + mf * 16 + lr;
        int rc = (rg < ne) ? rg : 0;
        aptr[mf] = act + (size_t)(roff + rc) * IDIM + lk * 8;
    }
    const float* bsrc = w2 + ((size_t)e * HDIM + d0 + br) * IDIM + bp * 8;

    short8 aE[5], aO[5];
    float4 bS0[2], bS1[2], bS2[2], bS3[2];
    f32x4  acc[5][4] = {};

    constexpr int NT = 64;   // IDIM / 32

    #pragma unroll
    for (int mf = 0; mf < 5; ++mf) aE[mf] = *(const short8*)(aptr[mf]);
    {
        float4 p0 = *(const float4*)(bsrc);
        float4 p1 = *(const float4*)(bsrc + 4);
        *(short8*)(&lB[0][br * 80 + bp * 16]) = cvt8(p0, p1);
    }
    bS1[0] = *(const float4*)(bsrc + 32);  bS1[1] = *(const float4*)(bsrc + 36);
    bS2[0] = *(const float4*)(bsrc + 64);  bS2[1] = *(const float4*)(bsrc + 68);
    asm volatile("s_waitcnt lgkmcnt(0)" ::: "memory");
    __builtin_amdgcn_s_barrier();

#define GSTEP(T_, AU, AP, SPUB, SISS)                                                    \
    {                                                                                    \
        const int t_ = (T_);                                                             \
        if (t_ + 1 < NT) {                                                               \
            _Pragma("unroll")                                                            \
            for (int mf = 0; mf < 5; ++mf)                                               \
                AP[mf] = *(const short8*)(aptr[mf] + (t_ + 1) * 32);                     \
        }                                                                                \
        if (t_ + 3 < NT) {                                                               \
            SISS[0] = *(const float4*)(bsrc + (t_ + 3) * 32);                            \
            SISS[1] = *(const float4*)(bsrc + (t_ + 3) * 32 + 4);                        \
        }                                                                                \
        __builtin_amdgcn_sched_barrier(0);                                               \
        if (t_ + 1 < NT)                                                                 \
            *(short8*)(&lB[(t_ + 1) & 1][br * 80 + bp * 16]) = cvt8(SPUB[0], SPUB[1]);   \
        short8 bfr[4];                                                                   \
        _Pragma("unroll")                                                                \
        for (int n = 0; n < 4; ++n)                                                      \
            bfr[n] = *(const short8*)(&lB[t_ & 1][(n * 16 + lr) * 80 + lk * 16]);        \
        _Pragma("unroll")                                                                \
        for (int mf = 0; mf < 5; ++mf)                                                   \
            _Pragma("unroll")                                                            \
            for (int n = 0; n < 4; ++n)                                                  \
                acc[mf][n] = __builtin_amdgcn_mfma_f32_16x16x32_bf16(                    \
                    AU[mf], bfr[n], acc[mf][n], 0, 0, 0);                                \
        asm volatile("s_waitcnt lgkmcnt(0)" ::: "memory");                               \
        __builtin_amdgcn_s_barrier();                                                    \
    }

    for (int t4 = 0; t4 < NT / 4; ++t4) {
        const int tb = t4 * 4;
        GSTEP(tb + 0, aE, aO, bS1, bS3)
        GSTEP(tb + 1, aO, aE, bS2, bS0)
        GSTEP(tb + 2, aE, aO, bS3, bS1)
        GSTEP(tb + 3, aO, aE, bS0, bS2)
    }
#undef GSTEP

    #pragma unroll
    for (int mf = 0; mf < 5; ++mf) {
        #pragma unroll
        for (int r = 0; r < 4; ++r) {
            const int rg = brow + wv * 80 + mf * 16 + lk * 4 + r;
            if (rg >= ne) continue;
            unsigned short* yrow = ybuf + (size_t)(roff + rg) * HDIM;
            #pragma unroll
            for (int n = 0; n < 4; ++n) {
                const int d = d0 + n * 16 + lr;
                yrow[d] = f2bf(acc[mf][n][r] + b2[(size_t)e * HDIM + d]);
            }
        }
    }
}

// ---------------- combine: out = x + sum_k gate_k * ybuf[row_k] ----------------
__global__ __launch_bounds__(256) void k_comb(
    const float* __restrict__ x, const unsigned short* __restrict__ ybuf,
    const int* __restrict__ rowidx, const float* __restrict__ gate_mk,
    float* __restrict__ out)
{
    __shared__ int   rws[TOPK];
    __shared__ float gws[TOPK];
    const int m = blockIdx.x;
    const int tid = threadIdx.x;
    if (tid < TOPK) {
        rws[tid] = rowidx[m * TOPK + tid];
        gws[tid] = gate_mk[m * TOPK + tid];
    }
    __syncthreads();
    const int d = tid * 8;
    float4 o0 = ((const float4*)(x + (size_t)m * HDIM + d))[0];
    float4 o1 = ((const float4*)(x + (size_t)m * HDIM + d))[1];
    #pragma unroll
    for (int k = 0; k < TOPK; ++k) {
        const float g = gws[k];
        short8 y = *(const short8*)(ybuf + (size_t)rws[k] * HDIM + d);
        float yv[8];
        #pragma unroll
        for (int j = 0; j < 8; ++j) {
            unsigned u = ((unsigned)(unsigned short)y[j]) << 16;
            yv[j] = __builtin_bit_cast(float, u);
        }
        o0.x += g * yv[0]; o0.y += g * yv[1]; o0.z += g * yv[2]; o0.w += g * yv[3];
        o1.x += g * yv[4]; o1.y += g * yv[5]; o1.z += g * yv[6]; o1.w += g * yv[7];
    }
    ((float4*)(out + (size_t)m * HDIM + d))[0] = o0;
    ((float4*)(out + (size_t)m * HDIM + d))[1] = o1;
}

extern "C" void kernel_launch(void* const* d_in, const int* in_sizes, int n_in,
                              void* d_out, int out_size, void* d_ws, size_t ws_size,
                              hipStream_t stream) {
    const float* x      = (const float*)d_in[0];
    const float* norm_w = (const float*)d_in[1];
    const float* gate_w = (const float*)d_in[2];
    const float* gate_b = (const float*)d_in[3];
    const float* w1     = (const float*)d_in[4];
    const float* b1     = (const float*)d_in[5];
    const float* w2     = (const float*)d_in[6];
    const float* b2     = (const float*)d_in[7];
    float* out = (float*)d_out;

    char* ws = (char*)d_ws;
    size_t off = 0;
    unsigned short* t_bf = (unsigned short*)(ws + off); off += (size_t)MTOK * HDIM * 2;  // 4 MB
    unsigned short* actb = (unsigned short*)(ws + off); off += (size_t)NA * IDIM * 2;    // 16.8 MB
    unsigned short* ybuf = (unsigned short*)(ws + off); off += (size_t)NA * HDIM * 2;    // 16.8 MB
    int*   counts   = (int*)(ws + off);   off += 256;
    int*   idx_of   = (int*)(ws + off);   off += (size_t)NA * 4;
    int*   slot_of  = (int*)(ws + off);   off += (size_t)NA * 4;
    float* gate_mk  = (float*)(ws + off); off += (size_t)NA * 4;
    int*   token_of = (int*)(ws + off);   off += (size_t)NA * 4;
    int*   rowidx   = (int*)(ws + off);   off += (size_t)NA * 4;

    (void)hipMemsetAsync(counts, 0, 256, stream);
    k_router<<<MTOK, 256, 0, stream>>>(x, norm_w, gate_w, gate_b, t_bf,
                                       counts, idx_of, slot_of, gate_mk);
    k_remap<<<NA / 256, 256, 0, stream>>>(idx_of, slot_of, counts,
                                          token_of, rowidx);
    k_gemm1<<<dim3(IDIM / 32, (MTOK + 319) / 320, NEXP), 256, 0, stream>>>(
        t_bf, w1, b1, counts, token_of, actb);
    k_gemm2<<<dim3(HDIM / 64, (MTOK + 319) / 320, NEXP), 256, 0, stream>>>(
        actb, w2, b2, counts, token_of, ybuf);
    k_comb<<<MTOK, 256, 0, stream>>>(x, ybuf, rowidx, gate_mk, out);
}